// Round 11
// baseline (85.561 us; speedup 1.0000x reference)
//
#include <hip/hip_runtime.h>
#include <math.h>

#define NBINS   15
#define CDIM    1000
#define QDIM    250                 // CDIM / 4
#define HIST_ELEMS (NBINS * CDIM)
#define THREADS 256
#define NWAVES  (THREADS / 64)      // 4 waves per block
#define PAD     -1000.0f            // exp(PAD) == 0 exactly -> conf == 0 -> add == 0

__device__ __forceinline__ float waveSum(float v) {
#pragma unroll
    for (int o = 32; o > 0; o >>= 1) v += __shfl_xor(v, o, 64);
    return v;
}

// Hot path byte-identical to the proven 71 us kernel (r10): exp pass
// (+1 v_max/elem), wave sum, rare-row test, ONE fmaf per element into regAcc.
// Label correction = single lane-guarded ds_add(-1.0) into sB (valid in
// common path: !rare => all conf <= 1/15 => label is bin 0). Rare rows
// (~85 of 65536) run the verified baseline per-element logic.
//
// STRUCTURAL CHANGE vs r10 (the last untried occupancy access point):
// the 3-buffer software pipeline (48 VGPR) is DELETED. Minimal live set
// (~50-60 hand-counted: one row buffer + regAcc + overhead) is bet against
// cap-102 from __launch_bounds__(256,5) -> 5 blocks/CU = 20 waves/CU.
// Latency hiding moves from per-wave ILP to TLP, the reference-streaming-
// kernel recipe. Failure modes are binary and readable: spill (VGPR<=64,
// >140us) or flat-at-higher-occupancy (~72us) -> revert & declare.
__device__ __forceinline__ void computeRow(float4 (&v)[4], int label, int lane,
                                           float (&regAcc)[4][4],
                                           float* __restrict__ sB,
                                           float* __restrict__ D) {
    float s = 0.0f, m = 0.0f;
#pragma unroll
    for (int j = 0; j < 4; ++j) {
        v[j].x = __expf(v[j].x);
        v[j].y = __expf(v[j].y);
        v[j].z = __expf(v[j].z);
        v[j].w = __expf(v[j].w);
        s += (v[j].x + v[j].y) + (v[j].z + v[j].w);
        m = fmaxf(m, fmaxf(fmaxf(v[j].x, v[j].y), fmaxf(v[j].z, v[j].w)));
    }
    s = waveSum(s);
    const float inv = 1.0f / s;

    // Exact: RN mul by positive inv / 15 is monotone, so max-of-predicate ==
    // predicate-of-max; expression shape matches the per-element test exactly.
    const float cmax = m * inv;
    const bool  rare = __any(cmax * 15.0f > 1.0f);

    if (!rare) {
        // Common path: every element lands in bin 0. One v_fmac each.
#pragma unroll
        for (int j = 0; j < 4; ++j) {
            regAcc[j][0] = fmaf(v[j].x, inv, regAcc[j][0]);
            regAcc[j][1] = fmaf(v[j].y, inv, regAcc[j][1]);
            regAcc[j][2] = fmaf(v[j].z, inv, regAcc[j][2]);
            regAcc[j][3] = fmaf(v[j].w, inv, regAcc[j][3]);
        }
        // Label correction: owning lane subtracts 1.0 in LDS (bin-0 slot).
        const int lq = label >> 2;           // quad index 0..249
        const int lk = label & 3;            // component
        if (lane == (lq & 63))
            unsafeAtomicAdd(&sB[lk * QDIM + lq], -1.0f);
    } else {
        // Rare row: full per-element bin logic (verified baseline code).
#pragma unroll
        for (int j = 0; j < 4; ++j) {
            const int q = lane + 64 * j;
            const float cf[4] = {v[j].x, v[j].y, v[j].z, v[j].w};
#pragma unroll
            for (int k = 0; k < 4; ++k) {
                float conf = cf[k] * inv;
                float t    = conf * 15.0f;
                float add  = conf - ((4 * q + k == label) ? 1.0f : 0.0f);
                if (t > 1.0f) {
                    int b = min((int)ceilf(t) - 1, NBINS - 1);
                    unsafeAtomicAdd(&D[b * CDIM + k * QDIM + q], add);
                } else {
                    regAcc[j][k] += add;
                }
            }
        }
    }
}

// Global D layout: index = b*CDIM + k*QDIM + q, class c = 4*q + k (bijective;
// the final sum of |D| is layout-invariant). sB mirrors the b == 0 plane.
// 256-thread blocks, cap-102 (5 waves/EU): natural demand of the
// de-pipelined shape (~50-60 + allocator inflation) should fit.
__global__ __launch_bounds__(THREADS, 5) void ece_hist_kernel(
        const float* __restrict__ logits,
        const int*   __restrict__ labels,
        float*       __restrict__ D,
        int N, int rowsPerBlock)
{
    __shared__ float sB[CDIM];           // 4 KB: block-level bin-0 reduce

    const int tid  = threadIdx.x;
    const int lane = tid & 63;
    const int w    = tid >> 6;           // wave id 0..3

    for (int i = tid; i < CDIM; i += THREADS) sB[i] = 0.0f;
    __syncthreads();

    const int r0 = blockIdx.x * rowsPerBlock;
    const int r1 = min(r0 + rowsPerBlock, N);

    float regAcc[4][4];
#pragma unroll
    for (int j = 0; j < 4; ++j)
#pragma unroll
        for (int k = 0; k < 4; ++k) regAcc[j][k] = 0.0f;

    // --- NO software pipeline: one row buffer, minimal live set; latency
    //     hiding comes from 20 waves/CU (TLP). Unroll disabled so the
    //     compiler cannot re-inflate the live set by interleaving rows.
#pragma clang loop unroll(disable)
    for (int r = r0 + w; r < r1; r += NWAVES) {
        float4 v[4];
        const float4* row = (const float4*)(logits + (size_t)r * CDIM);
        v[0] = row[lane];
        v[1] = row[lane + 64];
        v[2] = row[lane + 128];                  // q <= 191 < QDIM always
        v[3] = (lane < QDIM - 192) ? row[lane + 192]
                                   : make_float4(PAD, PAD, PAD, PAD);
        const int label = labels[r];

        computeRow(v, label, lane, regAcc, sB, D);
    }

    // Block-level reduce of bin-0 registers (once per block, native ds_add).
#pragma unroll
    for (int j = 0; j < 4; ++j) {
        int q = lane + 64 * j;
        if (q < QDIM) {
#pragma unroll
            for (int k = 0; k < 4; ++k)
                unsafeAtomicAdd(&sB[k * QDIM + q], regAcc[j][k]);
        }
    }

    __syncthreads();
    // Flush bin-0 partials to global (1000 atomics per non-empty block).
    for (int i = tid; i < CDIM; i += THREADS) {
        float val = sB[i];
        if (val != 0.0f) unsafeAtomicAdd(&D[i], val);
    }
}

__global__ __launch_bounds__(1024) void ece_final_kernel(
        const float* __restrict__ D, float* __restrict__ out, float scale)
{
    float s = 0.0f;
    const float4* D4 = (const float4*)D;     // HIST_ELEMS % 4 == 0
    for (int i = threadIdx.x; i < HIST_ELEMS / 4; i += 1024) {
        float4 t = D4[i];
        s += (fabsf(t.x) + fabsf(t.y)) + (fabsf(t.z) + fabsf(t.w));
    }
    s = waveSum(s);
    __shared__ float sr[16];
    const int lane = threadIdx.x & 63;
    const int wid  = threadIdx.x >> 6;
    if (lane == 0) sr[wid] = s;
    __syncthreads();
    if (threadIdx.x == 0) {
        float t = 0.0f;
#pragma unroll
        for (int ww = 0; ww < 16; ++ww) t += sr[ww];
        out[0] = t * scale;
    }
}

extern "C" void kernel_launch(void* const* d_in, const int* in_sizes, int n_in,
                              void* d_out, int out_size, void* d_ws, size_t ws_size,
                              hipStream_t stream)
{
    const float* logits = (const float*)d_in[0];
    const int*   labels = (const int*)d_in[1];

    const int N = in_sizes[1];                        // 65536 rows

    float* D = (float*)d_ws;
    hipMemsetAsync(D, 0, HIST_ELEMS * sizeof(float), stream);

    const int grid = 1280;                            // 5 blocks/CU target, 13 rows/wave
    const int rowsPerBlock = (N + grid - 1) / grid;   // 52

    ece_hist_kernel<<<grid, THREADS, 0, stream>>>(logits, labels, D, N, rowsPerBlock);

    const float scale = 1.0f / ((float)N * (float)CDIM);
    ece_final_kernel<<<1, 1024, 0, stream>>>(D, (float*)d_out, scale);
}